// Round 3
// baseline (259.231 us; speedup 1.0000x reference)
//
#include <hip/hip_runtime.h>

// CrossCompressUnit: rank-1 cross projections.
//   v_out = v * (e.w_vv) + e * (v.w_ev) + b_v
//   e_out = v * (e.w_ve) + e * (v.w_ee) + b_e
// B = 131072 rows, D = 128, f32.
//
// Round 3: DECISIVE EXPERIMENT. Fused kernel was pinned at 3.3 TB/s combined
// (half of copy rate) across two different structures. Split into two
// copy-shaped kernels:
//   K1 (ccu_dots):  read v,e -> per-row float4 {e.wvv, v.wev, e.wve, v.wee}
//                   into d_ws (2 MB, L2/L3-resident).
//   K2 (ccu_apply): read v,e (L3-hot from K1) + dots -> FMA -> write outputs.
//                   Zero cross-lane ops; pure stream. Its rate tells us whether
//                   3.3 TB/s was a structure artifact or the true mixed roofline.

#define CCU_D 128
#define K1_ROWS 2   // rows per 32-lane group in K1

__device__ __forceinline__ float dot4(const float4 a, const float4 b) {
    return a.x * b.x + a.y * b.y + a.z * b.z + a.w * b.w;
}

__global__ __launch_bounds__(256) void ccu_dots(
    const float* __restrict__ v,
    const float* __restrict__ e,
    const float* __restrict__ w_vv,
    const float* __restrict__ w_ev,
    const float* __restrict__ w_ve,
    const float* __restrict__ w_ee,
    float4* __restrict__ dots,       // [nrows] {e.wvv, v.wev, e.wve, v.wee}
    int nrows)
{
    const int lane32 = threadIdx.x & 31;
    const int group  = (int)((blockIdx.x * (size_t)blockDim.x + threadIdx.x) >> 5);
    const int base   = group * K1_ROWS;
    if (base >= nrows) return;

    const float4 wvv = ((const float4*)w_vv)[lane32];
    const float4 wev = ((const float4*)w_ev)[lane32];
    const float4 wve = ((const float4*)w_ve)[lane32];
    const float4 wee = ((const float4*)w_ee)[lane32];

    float4 vr[K1_ROWS], er[K1_ROWS];
    #pragma unroll
    for (int k = 0; k < K1_ROWS; ++k) {
        vr[k] = ((const float4*)(v + (size_t)(base + k) * CCU_D))[lane32];
        er[k] = ((const float4*)(e + (size_t)(base + k) * CCU_D))[lane32];
    }

    float dvv[K1_ROWS], dev[K1_ROWS], dve[K1_ROWS], dee[K1_ROWS];
    #pragma unroll
    for (int k = 0; k < K1_ROWS; ++k) {
        dvv[k] = dot4(er[k], wvv);
        dev[k] = dot4(vr[k], wev);
        dve[k] = dot4(er[k], wve);
        dee[k] = dot4(vr[k], wee);
    }

    #pragma unroll
    for (int off = 16; off >= 1; off >>= 1) {
        #pragma unroll
        for (int k = 0; k < K1_ROWS; ++k) {
            dvv[k] += __shfl_xor(dvv[k], off);
            dev[k] += __shfl_xor(dev[k], off);
            dve[k] += __shfl_xor(dve[k], off);
            dee[k] += __shfl_xor(dee[k], off);
        }
    }

    if (lane32 == 0) {
        #pragma unroll
        for (int k = 0; k < K1_ROWS; ++k) {
            float4 d;
            d.x = dvv[k]; d.y = dev[k]; d.z = dve[k]; d.w = dee[k];
            dots[base + k] = d;
        }
    }
}

// Pure-stream apply: one thread per float4 of the row dimension.
__global__ __launch_bounds__(256) void ccu_apply(
    const float* __restrict__ v,
    const float* __restrict__ e,
    const float4* __restrict__ dots,
    const float* __restrict__ b_v,
    const float* __restrict__ b_e,
    float* __restrict__ v_out,
    float* __restrict__ e_out,
    int nvec4)                        // nrows * (D/4)
{
    const int g = (int)(blockIdx.x * (size_t)blockDim.x + threadIdx.x);
    if (g >= nvec4) return;
    const int c   = g & 31;           // float4 index within row
    const int row = g >> 5;

    const float4 vr = ((const float4*)v)[g];
    const float4 er = ((const float4*)e)[g];
    const float4 d  = dots[row];      // broadcast across the row's 32 lanes
    const float4 bv = ((const float4*)b_v)[c];
    const float4 be = ((const float4*)b_e)[c];

    float4 vo, eo;
    vo.x = vr.x * d.x + er.x * d.y + bv.x;
    vo.y = vr.y * d.x + er.y * d.y + bv.y;
    vo.z = vr.z * d.x + er.z * d.y + bv.z;
    vo.w = vr.w * d.x + er.w * d.y + bv.w;

    eo.x = vr.x * d.z + er.x * d.w + be.x;
    eo.y = vr.y * d.z + er.y * d.w + be.y;
    eo.z = vr.z * d.z + er.z * d.w + be.z;
    eo.w = vr.w * d.z + er.w * d.w + be.w;

    ((float4*)v_out)[g] = vo;
    ((float4*)e_out)[g] = eo;
}

extern "C" void kernel_launch(void* const* d_in, const int* in_sizes, int n_in,
                              void* d_out, int out_size, void* d_ws, size_t ws_size,
                              hipStream_t stream) {
    const float* v    = (const float*)d_in[0];
    const float* e    = (const float*)d_in[1];
    const float* w_vv = (const float*)d_in[2];
    const float* w_ev = (const float*)d_in[3];
    const float* w_ve = (const float*)d_in[4];
    const float* w_ee = (const float*)d_in[5];
    const float* b_v  = (const float*)d_in[6];
    const float* b_e  = (const float*)d_in[7];

    const int nrows = in_sizes[0] / CCU_D;          // 131072
    float* v_out = (float*)d_out;
    float* e_out = (float*)d_out + (size_t)nrows * CCU_D;
    float4* dots = (float4*)d_ws;                   // 2 MB

    // K1: 256 threads = 8 groups * 2 rows = 16 rows/block.
    const int k1_rows_per_block = (256 / 32) * K1_ROWS;
    const int k1_blocks = (nrows + k1_rows_per_block - 1) / k1_rows_per_block;
    ccu_dots<<<k1_blocks, 256, 0, stream>>>(v, e, w_vv, w_ev, w_ve, w_ee,
                                            dots, nrows);

    // K2: one thread per float4; nrows*32 threads.
    const int nvec4 = nrows * (CCU_D / 4);
    const int k2_blocks = (nvec4 + 255) / 256;
    ccu_apply<<<k2_blocks, 256, 0, stream>>>(v, e, dots, b_v, b_e,
                                             v_out, e_out, nvec4);
}

// Round 4
// 230.247 us; speedup vs baseline: 1.1259x; 1.1259x over previous
//
#include <hip/hip_runtime.h>

// CrossCompressUnit: rank-1 cross projections.
//   v_out = v * (e.w_vv) + e * (v.w_ev) + b_v
//   e_out = v * (e.w_ve) + e * (v.w_ee) + b_e
// B = 131072 rows, D = 128, f32. Demand traffic 268 MB -> ~43 us at copy rate.
//
// Round 4: NONTEMPORAL experiment. Theory: the harness poisons d_ws (537 MB) +
// d_out (134 MB) to 0xAA before every timed launch, filling the 256 MB
// memory-side Infinity Cache with dirty lines. Every allocation our kernel
// makes (v read-miss fills, output write-allocates) evicts a dirty poison
// line -> hidden HBM writeback invisible to TCC counters. Measured 80.4 us
// = ~400 MB real HBM traffic = near-peak on traffic we didn't order.
// Fix: nt loads for v/e and nt stores for outputs bypass cache allocation,
// eliminating the forced poison writebacks. Kernel is otherwise IDENTICAL
// to round 2 for a clean A/B.

#define CCU_D 128
#define ROWS_PER_GROUP 4

typedef float f4 __attribute__((ext_vector_type(4)));

__device__ __forceinline__ float dot4v(const f4 a, const f4 b) {
    return a.x * b.x + a.y * b.y + a.z * b.z + a.w * b.w;
}

__global__ __launch_bounds__(256) void ccu_kernel(
    const float* __restrict__ v,
    const float* __restrict__ e,
    const float* __restrict__ w_vv,
    const float* __restrict__ w_ev,
    const float* __restrict__ w_ve,
    const float* __restrict__ w_ee,
    const float* __restrict__ b_v,
    const float* __restrict__ b_e,
    float* __restrict__ v_out,
    float* __restrict__ e_out,
    int nrows)
{
    const int lane32 = threadIdx.x & 31;   // 16B column group within row
    const int group  = (int)((blockIdx.x * (size_t)blockDim.x + threadIdx.x) >> 5);
    const int base   = group * ROWS_PER_GROUP;
    if (base >= nrows) return;

    // Weights/biases: tiny, reused by every wave -> NORMAL (cached) loads.
    const f4 wvv = ((const f4*)w_vv)[lane32];
    const f4 wev = ((const f4*)w_ev)[lane32];
    const f4 wve = ((const f4*)w_ve)[lane32];
    const f4 wee = ((const f4*)w_ee)[lane32];

    // Streaming data: NONTEMPORAL loads (no cache allocation -> no poison
    // eviction on miss fill).
    f4 vr[ROWS_PER_GROUP], er[ROWS_PER_GROUP];
    #pragma unroll
    for (int k = 0; k < ROWS_PER_GROUP; ++k) {
        vr[k] = __builtin_nontemporal_load(
                    (const f4*)(v + (size_t)(base + k) * CCU_D) + lane32);
        er[k] = __builtin_nontemporal_load(
                    (const f4*)(e + (size_t)(base + k) * CCU_D) + lane32);
    }

    float dvv[ROWS_PER_GROUP], dev[ROWS_PER_GROUP];
    float dve[ROWS_PER_GROUP], dee[ROWS_PER_GROUP];
    #pragma unroll
    for (int k = 0; k < ROWS_PER_GROUP; ++k) {
        dvv[k] = dot4v(er[k], wvv);
        dev[k] = dot4v(vr[k], wev);
        dve[k] = dot4v(er[k], wve);
        dee[k] = dot4v(vr[k], wee);
    }

    // Butterfly reduce across the 32 lanes of each row (16 interleaved chains).
    #pragma unroll
    for (int off = 16; off >= 1; off >>= 1) {
        #pragma unroll
        for (int k = 0; k < ROWS_PER_GROUP; ++k) {
            dvv[k] += __shfl_xor(dvv[k], off);
            dev[k] += __shfl_xor(dev[k], off);
            dve[k] += __shfl_xor(dve[k], off);
            dee[k] += __shfl_xor(dee[k], off);
        }
    }

    const f4 bv = ((const f4*)b_v)[lane32];
    const f4 be = ((const f4*)b_e)[lane32];

    #pragma unroll
    for (int k = 0; k < ROWS_PER_GROUP; ++k) {
        f4 vo, eo;
        vo.x = vr[k].x * dvv[k] + er[k].x * dev[k] + bv.x;
        vo.y = vr[k].y * dvv[k] + er[k].y * dev[k] + bv.y;
        vo.z = vr[k].z * dvv[k] + er[k].z * dev[k] + bv.z;
        vo.w = vr[k].w * dvv[k] + er[k].w * dev[k] + bv.w;

        eo.x = vr[k].x * dve[k] + er[k].x * dee[k] + be.x;
        eo.y = vr[k].y * dve[k] + er[k].y * dee[k] + be.y;
        eo.z = vr[k].z * dve[k] + er[k].z * dee[k] + be.z;
        eo.w = vr[k].w * dve[k] + er[k].w * dee[k] + be.w;

        // NONTEMPORAL stores: stream to HBM without L3 write-allocate ->
        // no dirty-poison eviction.
        __builtin_nontemporal_store(
            vo, (f4*)(v_out + (size_t)(base + k) * CCU_D) + lane32);
        __builtin_nontemporal_store(
            eo, (f4*)(e_out + (size_t)(base + k) * CCU_D) + lane32);
    }
}

extern "C" void kernel_launch(void* const* d_in, const int* in_sizes, int n_in,
                              void* d_out, int out_size, void* d_ws, size_t ws_size,
                              hipStream_t stream) {
    const float* v    = (const float*)d_in[0];
    const float* e    = (const float*)d_in[1];
    const float* w_vv = (const float*)d_in[2];
    const float* w_ev = (const float*)d_in[3];
    const float* w_ve = (const float*)d_in[4];
    const float* w_ee = (const float*)d_in[5];
    const float* b_v  = (const float*)d_in[6];
    const float* b_e  = (const float*)d_in[7];

    const int nrows = in_sizes[0] / CCU_D;          // 131072
    float* v_out = (float*)d_out;
    float* e_out = (float*)d_out + (size_t)nrows * CCU_D;

    // 8 groups/block * 4 rows/group = 32 rows per 256-thread block.
    const int rows_per_block = (256 / 32) * ROWS_PER_GROUP;
    const int blocks = (nrows + rows_per_block - 1) / rows_per_block;  // 4096
    ccu_kernel<<<blocks, 256, 0, stream>>>(v, e, w_vv, w_ev, w_ve, w_ee,
                                           b_v, b_e, v_out, e_out, nrows);
}